// Round 14
// baseline (382.250 us; speedup 1.0000x reference)
//
#include <hip/hip_runtime.h>

#define BB 32
#define DD 400
#define KK 200
#define NN (BB*KK)
#define NBINS 512
#define NSIMD 1024  // 256 CU x 4 SIMD

typedef _Float16 half_t;
typedef _Float16 f16x2 __attribute__((ext_vector_type(2)));

__device__ __forceinline__ float dot2(f16x2 w, f16x2 v, float acc) {
  return __builtin_amdgcn_fdot2(w, v, acc, false);
}
__device__ __forceinline__ f16x2 bc16(int v) { return __builtin_bit_cast(f16x2, v); }
__device__ __forceinline__ int pkh(float a, float b) {
  return __builtin_bit_cast(int, __builtin_amdgcn_cvt_pkrtz(a, b));
}

__device__ __forceinline__ float fast_sigmoid(float x) {
  float e = __builtin_amdgcn_exp2f(-1.4426950408889634f * x);
  return __builtin_amdgcn_rcpf(1.0f + e);
}
__device__ __forceinline__ float fast_tanh(float x) {
  float e = __builtin_amdgcn_exp2f(-2.8853900817779268f * x);
  return 2.0f * __builtin_amdgcn_rcpf(1.0f + e) - 1.0f;
}

// quad_perm broadcast P within each aligned 4-lane quad (VALU pipe), int form
#define QPERMI(v, P) __builtin_amdgcn_mov_dpp((v), (P)*0x55, 0xF, 0xF, true)
// ROW_HALF_MIRROR: lane i reads lane i^7 within each 8-lane half-row (VALU pipe)
#define HMIRROR(v) __int_as_float(__builtin_amdgcn_mov_dpp(__float_as_int(v), 0x141, 0xF, 0xF, true))

// x (B, D, K) -> xt[(b*K+k)*D + t] = x[b][t][k]
__global__ __launch_bounds__(256) void transpose_x(const float* __restrict__ x,
                                                   float* __restrict__ xt) {
  __shared__ float tile[32][33];
  int b = blockIdx.x, t0 = blockIdx.y * 32, k0 = blockIdx.z * 32;
  int tx = threadIdx.x, ty = threadIdx.y;
#pragma unroll
  for (int i = 0; i < 32; i += 8) {
    int t = t0 + ty + i, k = k0 + tx;
    tile[ty + i][tx] = (t < DD && k < KK) ? x[((size_t)b * DD + t) * KK + k] : 0.0f;
  }
  __syncthreads();
#pragma unroll
  for (int i = 0; i < 32; i += 8) {
    int k = k0 + ty + i, t = t0 + tx;
    if (k < KK && t < DD) xt[((size_t)b * KK + k) * DD + t] = tile[tx][ty + i];
  }
}

// first zero index (else D) per sequence + length histogram
__global__ __launch_bounds__(64) void compute_lengths(const float* __restrict__ xt,
                                                      int* __restrict__ lengths,
                                                      int* __restrict__ hist) {
  int n = blockIdx.x, lane = threadIdx.x;
  int m = DD;
  for (int t = lane; t < DD; t += 64) {
    if (xt[(size_t)n * DD + t] == 0.0f) { m = t; break; }
  }
#pragma unroll
  for (int off = 1; off < 64; off <<= 1) {
    int o = __shfl_xor(m, off, 64);
    m = (o < m) ? o : m;
  }
  if (lane == 0) {
    lengths[n] = m;
    atomicAdd(&hist[m], 1);
  }
}

// wave-parallel exclusive prefix scan over 512 bins (8 bins/lane + shfl scan)
__global__ __launch_bounds__(64) void scan_offsets(const int* __restrict__ hist,
                                                   int* __restrict__ offs) {
  int lane = threadIdx.x;
  int v[8], tot = 0;
#pragma unroll
  for (int i = 0; i < 8; ++i) { v[i] = tot; tot += hist[lane * 8 + i]; }
  int incl = tot;
#pragma unroll
  for (int off = 1; off < 64; off <<= 1) {
    int oth = __shfl_up(incl, off, 64);
    if (lane >= off) incl += oth;
  }
  int excl = incl - tot;
#pragma unroll
  for (int i = 0; i < 8; ++i) offs[lane * 8 + i] = excl + v[i];
}

__global__ __launch_bounds__(256) void scatter_sort(const int* __restrict__ lengths,
                                                    int* __restrict__ offs,
                                                    int* __restrict__ order,
                                                    int* __restrict__ len_sorted) {
  int n = blockIdx.x * 256 + threadIdx.x;
  if (n >= NN) return;
  int len = lengths[n];
  int pos = atomicAdd(&offs[len], 1);
  order[pos] = n;
  len_sorted[pos] = len;
}

// SIMD-aware wave->octet mapping (1 wave per block; XCD round-robin means
// p and p+NSIMD co-reside). Singles get longest octets; pairs sum ~constant.
__device__ __forceinline__ int octet_of_wave(int p, int W) {
  int E = W - NSIMD;
  if (E <= 0) return W - 1 - p;                 // all singles: desc
  if (p >= NSIMD) return p - NSIMD;             // pair minor: shortest E
  if (p >= E) return W - 1 - (p - E);           // singles: longest
  return (W - 1 - NSIMD + E) - p;               // pair major
}

// ===== dir-major slab layout =====
// buf[oct4][t][dir][32] halfs; slot (sg&3)*8+li. Wave-step store -> 2
// contiguous 64B segments. Consumer reads 16B at +0 (fwd) / +64B (bwd).

// 8 lanes per (sorted-seq, dir); lane li owns hidden unit li. 1 wave per block.
// __launch_bounds__(64,2): we use at most 2 waves/SIMD -> VGPR budget 256,
// letting the allocator pin weights + prefetch buffers (no rematerialization).
template <int IN_DIM, bool IND_IN, bool WRITE_SEQ, bool FWD_ONLY>
__global__ __launch_bounds__(64, 2) void gru_scan(
    const void* __restrict__ in, half_t* __restrict__ out, float* __restrict__ feat,
    const int* __restrict__ len_sorted, const int* __restrict__ order,
    const float* __restrict__ Wih, const float* __restrict__ Whh,
    const float* __restrict__ bih, const float* __restrict__ bhh, int nseq) {
  int p = blockIdx.x;                 // one wave per block
  int lane = threadIdx.x & 63;
  int G = FWD_ONLY ? nseq : nseq * 2;
  int W = (G + 7) >> 3;
  if (p >= W) return;
  int o = octet_of_wave(p, W);
  int gidx = o * 8 + (lane >> 3);
  int li = lane & 7;
  if (gidx >= G) return;
  int sg  = FWD_ONLY ? gidx : (gidx >> 1);
  int dir = FWD_ONLY ? 0 : (gidx & 1);
  int len = len_sorted[sg];

  int qb = li & 4;
  int wp[3][4];       // packed f16x2 {Whh[.,qb+P], Whh[.,(qb+P)^7]}
  f16x2 wi2[3][8];
  float wi1[3];
  float bs[3], bh2;   // bs[0..1] = bih+bhh, bs[2] = bih; bh2 = bhh n-gate
#pragma unroll
  for (int gt = 0; gt < 3; ++gt) {
    int row = dir * 24 + gt * 8 + li;
    if constexpr (IN_DIM == 16) {
#pragma unroll
      for (int q = 0; q < 8; ++q) {
        f16x2 w;
        w.x = (half_t)Wih[row * 16 + 2 * q];
        w.y = (half_t)Wih[row * 16 + 2 * q + 1];
        wi2[gt][q] = w;
      }
    } else {
      wi1[gt] = Wih[row];
    }
#pragma unroll
    for (int P = 0; P < 4; ++P)
      wp[gt][P] = pkh(Whh[row * 8 + qb + P], Whh[row * 8 + ((qb + P) ^ 7)]);
    bs[gt] = bih[row] + ((gt < 2) ? bhh[row] : 0.0f);
    if (gt == 2) bh2 = bhh[row];
  }

  int steps = len;  // >= 200 always
  float h = 0.0f;

  const float* px = nullptr;
  const half_t* pxh = nullptr;
  ptrdiff_t xstep;
  if constexpr (IN_DIM == 1) {
    const float* basep = (const float*)in + (IND_IN ? (size_t)order[sg] * DD : (size_t)sg * DD);
    px = basep + ((dir == 0) ? 0 : (len - 1));
    xstep = (dir == 0) ? 1 : -1;
  } else {
    const half_t* basep = (const half_t*)in + (size_t)(sg >> 2) * DD * 64 + (sg & 3) * 8;
    pxh = basep + (size_t)((dir == 0) ? 0 : (len - 1)) * 64;
    xstep = (dir == 0) ? 64 : -64;
  }

  half_t* pw = nullptr; ptrdiff_t wstep = 0;
  if constexpr (WRITE_SEQ) {
    pw = out + ((size_t)(sg >> 2) * DD + ((dir == 0) ? 0 : (len - 1))) * 64
             + dir * 32 + (sg & 3) * 8 + li;
    wstep = (dir == 0) ? 64 : -64;
  }

  // epilogue: packed-f16 h-gather + dot2 gh (r/z chains SEEDED with gi), store
  auto core = [&](float a0, float a1, float a2) {
    float hm = HMIRROR(h);
    int hp = pkh(h, hm);               // {h(own), h(lane^7)}
    f16x2 u0 = bc16(QPERMI(hp, 0));
    f16x2 u1 = bc16(QPERMI(hp, 1));
    f16x2 u2 = bc16(QPERMI(hp, 2));
    f16x2 u3 = bc16(QPERMI(hp, 3));

    float c0 = dot2(bc16(wp[0][3]), u3, dot2(bc16(wp[0][2]), u2,
               dot2(bc16(wp[0][1]), u1, dot2(bc16(wp[0][0]), u0, a0))));
    float c1 = dot2(bc16(wp[1][3]), u3, dot2(bc16(wp[1][2]), u2,
               dot2(bc16(wp[1][1]), u1, dot2(bc16(wp[1][0]), u0, a1))));
    float c2 = dot2(bc16(wp[2][3]), u3, dot2(bc16(wp[2][2]), u2,
               dot2(bc16(wp[2][1]), u1, dot2(bc16(wp[2][0]), u0, bh2))));

    float r = fast_sigmoid(c0);
    float z = fast_sigmoid(c1);
    float n = fast_tanh(a2 + r * c2);
    h = z * (h - n) + n;  // == (1-z)*n + z*h
    if constexpr (WRITE_SEQ) { *pw = (half_t)h; pw += wstep; }
  };

  if constexpr (IN_DIM == 1) {
    float s0_, s1_, s2_, s3_;
    auto ld = [&](float& S_) { S_ = *px; px += xstep; };
    auto st = [&](float& S_, bool pf) {
      float a0 = fmaf(wi1[0], S_, bs[0]);
      float a1 = fmaf(wi1[1], S_, bs[1]);
      float a2 = fmaf(wi1[2], S_, bs[2]);
      if (pf) ld(S_);
      core(a0, a1, a2);
    };
    ld(s0_); ld(s1_); ld(s2_); ld(s3_);
    int t = 0;
    for (; t + 4 <= steps; t += 4) {
      st(s0_, true); st(s1_, true); st(s2_, true); st(s3_, true);
    }
    int rem = steps - t;
    if (rem > 0) st(s0_, false);
    if (rem > 1) st(s1_, false);
    if (rem > 2) st(s2_, false);
  } else {
    uint4 b0_[2], b1_[2], b2_[2], b3_[2];
    auto ld = [&](uint4 (&B_)[2]) {
      const uint4* q4 = reinterpret_cast<const uint4*>(pxh);
      B_[0] = q4[0]; B_[1] = q4[4];   // fwd dims, bwd dims (+64B)
      pxh += xstep;
    };
    auto st = [&](uint4 (&B_)[2], bool pf) {
      float a0 = bs[0], a1 = bs[1], a2 = bs[2];
#pragma unroll
      for (int q = 0; q < 2; ++q) {
        f16x2 p0 = __builtin_bit_cast(f16x2, B_[q].x);
        f16x2 p1 = __builtin_bit_cast(f16x2, B_[q].y);
        f16x2 p2 = __builtin_bit_cast(f16x2, B_[q].z);
        f16x2 p3 = __builtin_bit_cast(f16x2, B_[q].w);
        a0 = dot2(wi2[0][4*q], p0, a0); a0 = dot2(wi2[0][4*q+1], p1, a0);
        a0 = dot2(wi2[0][4*q+2], p2, a0); a0 = dot2(wi2[0][4*q+3], p3, a0);
        a1 = dot2(wi2[1][4*q], p0, a1); a1 = dot2(wi2[1][4*q+1], p1, a1);
        a1 = dot2(wi2[1][4*q+2], p2, a1); a1 = dot2(wi2[1][4*q+3], p3, a1);
        a2 = dot2(wi2[2][4*q], p0, a2); a2 = dot2(wi2[2][4*q+1], p1, a2);
        a2 = dot2(wi2[2][4*q+2], p2, a2); a2 = dot2(wi2[2][4*q+3], p3, a2);
      }
      if (pf) ld(B_);
      core(a0, a1, a2);
    };
    ld(b0_); ld(b1_); ld(b2_); ld(b3_);
    int t = 0;
    for (; t + 4 <= steps; t += 4) {
      st(b0_, true); st(b1_, true); st(b2_, true); st(b3_, true);
    }
    int rem = steps - t;
    if (rem > 0) st(b0_, false);
    if (rem > 1) st(b1_, false);
    if (rem > 2) st(b2_, false);
  }

  if constexpr (!WRITE_SEQ) {
    feat[(size_t)order[sg] * 16 + dir * 8 + li] = h;
  }
}

// last layer, bwd direction: only t = len-1 matters and h0 = 0 => gh = bhh
__global__ __launch_bounds__(256) void bwd_last(
    const half_t* __restrict__ in, float* __restrict__ feat,
    const int* __restrict__ len_sorted, const int* __restrict__ order,
    const float* __restrict__ Wih, const float* __restrict__ bih,
    const float* __restrict__ bhh, int nseq) {
  int tid = blockIdx.x * blockDim.x + threadIdx.x;
  int sg = tid >> 3, li = tid & 7;
  if (sg >= nseq) return;
  int len = len_sorted[sg];
  const half_t* xp = in + ((size_t)(sg >> 2) * DD + (len - 1)) * 64 + (sg & 3) * 8;
  float xv[16];
#pragma unroll
  for (int j = 0; j < 8; ++j) { xv[j] = (float)xp[j]; xv[8 + j] = (float)xp[32 + j]; }
  float a[3], bh[3];
#pragma unroll
  for (int gt = 0; gt < 3; ++gt) {
    int row = 24 + gt * 8 + li;  // dir=1 rows
    const float* wpp = Wih + row * 16;
    float acc = bih[row];
#pragma unroll
    for (int j = 0; j < 16; ++j) acc = fmaf(wpp[j], xv[j], acc);
    a[gt] = acc;
    bh[gt] = bhh[row];
  }
  float r = fast_sigmoid(a[0] + bh[0]);
  float z = fast_sigmoid(a[1] + bh[1]);
  float n = fast_tanh(a[2] + r * bh[2]);
  float h = (1.0f - z) * n;
  feat[(size_t)order[sg] * 16 + 8 + li] = h;
}

__global__ __launch_bounds__(256) void head_kernel(
    const float* __restrict__ feat, const float* __restrict__ w1,
    const float* __restrict__ b1, const float* __restrict__ w2,
    const float* __restrict__ b2, float* __restrict__ out) {
  int n = blockIdx.x * blockDim.x + threadIdx.x;
  if (n >= NN) return;
  float f[16];
  const float4* p = reinterpret_cast<const float4*>(feat + (size_t)n * 16);
#pragma unroll
  for (int q = 0; q < 4; ++q) {
    float4 v = p[q];
    f[4*q] = v.x; f[4*q+1] = v.y; f[4*q+2] = v.z; f[4*q+3] = v.w;
  }
  float y[8];
#pragma unroll
  for (int o = 0; o < 8; ++o) {
    float s = b1[o];
#pragma unroll
    for (int j = 0; j < 16; ++j) s += f[j] * w1[o * 16 + j];
    y[o] = (s > 0.0f) ? s : 0.2f * s;
  }
#pragma unroll
  for (int o2 = 0; o2 < 8; ++o2) {
    float s = b2[o2];
#pragma unroll
    for (int o = 0; o < 8; ++o) s += y[o] * w2[o2 * 8 + o];
    out[(size_t)n * 8 + o2] = s;
  }
}

extern "C" void kernel_launch(void* const* d_in, const int* in_sizes, int n_in,
                              void* d_out, int out_size, void* d_ws, size_t ws_size,
                              hipStream_t stream) {
  const float* x      = (const float*)d_in[0];
  const float* w_ih0  = (const float*)d_in[1];
  const float* w_hh0  = (const float*)d_in[2];
  const float* b_ih0  = (const float*)d_in[3];
  const float* b_hh0  = (const float*)d_in[4];
  const float* w_ih   = (const float*)d_in[5];
  const float* w_hh   = (const float*)d_in[6];
  const float* b_ih   = (const float*)d_in[7];
  const float* b_hh   = (const float*)d_in[8];
  const float* lin1_w = (const float*)d_in[9];
  const float* lin1_b = (const float*)d_in[10];
  const float* lin2_w = (const float*)d_in[11];
  const float* lin2_b = (const float*)d_in[12];
  float* out = (float*)d_out;

  char* ws = (char*)d_ws;
  size_t off = 0;
  auto alloc = [&](size_t bytes) -> void* {
    void* p = ws + off;
    off += (bytes + 255) & ~(size_t)255;
    return p;
  };
  alloc(1024);  // front guard (backward prefetch overrun)
  float* xt         = (float*)alloc((size_t)NN * DD * sizeof(float) + 1024);
  int*   lengths    = (int*)  alloc((size_t)NN * sizeof(int));
  int*   hist       = (int*)  alloc(NBINS * sizeof(int));
  int*   offs       = (int*)  alloc(NBINS * sizeof(int));
  int*   order      = (int*)  alloc((size_t)NN * sizeof(int));
  int*   len_sorted = (int*)  alloc((size_t)NN * sizeof(int));
  float* feat       = (float*)alloc((size_t)NN * 16 * sizeof(float));
  size_t base = off;
  size_t per_seq = (size_t)DD * 16 * sizeof(half_t) * 2 + 1024;  // two f16 buffers
  int Nc = NN;
  if (base + (size_t)NN * per_seq + 8192 > ws_size) {
    size_t avail = (ws_size > base + 8192) ? (ws_size - base - 8192) : 0;
    size_t nc = avail / per_seq;
    if (nc < 4) nc = 4;
    if (nc > (size_t)NN) nc = NN;
    Nc = (int)(nc & ~(size_t)3);  // multiple of 4 (slab oct4 granularity)
  }
  alloc(1024);  // guard before bufA
  half_t* bufA = (half_t*)alloc((size_t)Nc * DD * 16 * sizeof(half_t) + 1024);
  half_t* bufB = (half_t*)alloc((size_t)Nc * DD * 16 * sizeof(half_t) + 1024);

  hipMemsetAsync(hist, 0, NBINS * sizeof(int), stream);
  dim3 gT(BB, (DD + 31) / 32, (KK + 31) / 32), bT(32, 8, 1);
  hipLaunchKernelGGL(transpose_x, gT, bT, 0, stream, x, xt);
  hipLaunchKernelGGL(compute_lengths, dim3(NN), dim3(64), 0, stream, xt, lengths, hist);
  hipLaunchKernelGGL(scan_offsets, dim3(1), dim3(64), 0, stream, hist, offs);
  hipLaunchKernelGGL(scatter_sort, dim3((NN + 255) / 256), dim3(256), 0, stream,
                     lengths, offs, order, len_sorted);

  for (int s0 = 0; s0 < NN; s0 += Nc) {
    int ns = (NN - s0 < Nc) ? (NN - s0) : Nc;
    int W2 = (ns * 2 + 7) / 8;           // bidir wave count (1 wave per block)
    int W1 = (ns + 7) / 8;               // fwd-only wave count
    int blk1 = (ns * 8 + 255) / 256;     // bwd_last
    gru_scan<1, true, true, false><<<W2, 64, 0, stream>>>(
        (const void*)xt, bufA, nullptr, len_sorted + s0, order + s0,
        w_ih0, w_hh0, b_ih0, b_hh0, ns);
    gru_scan<16, false, true, false><<<W2, 64, 0, stream>>>(
        (const void*)bufA, bufB, nullptr, len_sorted + s0, order + s0,
        w_ih + 0 * 2 * 24 * 16, w_hh + 0 * 2 * 24 * 8,
        b_ih + 0 * 2 * 24, b_hh + 0 * 2 * 24, ns);
    gru_scan<16, false, true, false><<<W2, 64, 0, stream>>>(
        (const void*)bufB, bufA, nullptr, len_sorted + s0, order + s0,
        w_ih + 1 * 2 * 24 * 16, w_hh + 1 * 2 * 24 * 8,
        b_ih + 1 * 2 * 24, b_hh + 1 * 2 * 24, ns);
    gru_scan<16, false, false, true><<<W1, 64, 0, stream>>>(
        (const void*)bufA, nullptr, feat, len_sorted + s0, order + s0,
        w_ih + 2 * 2 * 24 * 16, w_hh + 2 * 2 * 24 * 8,
        b_ih + 2 * 2 * 24, b_hh + 2 * 2 * 24, ns);
    hipLaunchKernelGGL(bwd_last, dim3(blk1), dim3(256), 0, stream,
                       bufA, feat, len_sorted + s0, order + s0,
                       w_ih + 2 * 2 * 24 * 16, b_ih + 2 * 2 * 24, b_hh + 2 * 2 * 24, ns);
  }
  hipLaunchKernelGGL(head_kernel, dim3((NN + 255) / 256), dim3(256), 0, stream,
                     feat, lin1_w, lin1_b, lin2_w, lin2_b, out);
}

// Round 15
// 372.748 us; speedup vs baseline: 1.0255x; 1.0255x over previous
//
#include <hip/hip_runtime.h>

#define BB 32
#define DD 400
#define KK 200
#define NN (BB*KK)
#define NBINS 512
#define NSIMD 1024  // 256 CU x 4 SIMD

typedef _Float16 half_t;
typedef _Float16 f16x2 __attribute__((ext_vector_type(2)));

__device__ __forceinline__ float dot2(f16x2 w, f16x2 v, float acc) {
  return __builtin_amdgcn_fdot2(w, v, acc, false);
}
__device__ __forceinline__ f16x2 bc16(int v) { return __builtin_bit_cast(f16x2, v); }
__device__ __forceinline__ int pkh(float a, float b) {
  return __builtin_bit_cast(int, __builtin_amdgcn_cvt_pkrtz(a, b));
}

__device__ __forceinline__ float fast_sigmoid(float x) {
  float e = __builtin_amdgcn_exp2f(-1.4426950408889634f * x);
  return __builtin_amdgcn_rcpf(1.0f + e);
}
__device__ __forceinline__ float fast_tanh(float x) {
  float e = __builtin_amdgcn_exp2f(-2.8853900817779268f * x);
  return 2.0f * __builtin_amdgcn_rcpf(1.0f + e) - 1.0f;
}

// quad_perm broadcast P within each aligned 4-lane quad (VALU pipe), int form
#define QPERMI(v, P) __builtin_amdgcn_mov_dpp((v), (P)*0x55, 0xF, 0xF, true)
// ROW_HALF_MIRROR: lane i reads lane i^7 within each 8-lane half-row (VALU pipe)
#define HMIRROR(v) __int_as_float(__builtin_amdgcn_mov_dpp(__float_as_int(v), 0x141, 0xF, 0xF, true))

// x (B, D, K) -> xt[(b*K+k)*D + t] = x[b][t][k]
__global__ __launch_bounds__(256) void transpose_x(const float* __restrict__ x,
                                                   float* __restrict__ xt) {
  __shared__ float tile[32][33];
  int b = blockIdx.x, t0 = blockIdx.y * 32, k0 = blockIdx.z * 32;
  int tx = threadIdx.x, ty = threadIdx.y;
#pragma unroll
  for (int i = 0; i < 32; i += 8) {
    int t = t0 + ty + i, k = k0 + tx;
    tile[ty + i][tx] = (t < DD && k < KK) ? x[((size_t)b * DD + t) * KK + k] : 0.0f;
  }
  __syncthreads();
#pragma unroll
  for (int i = 0; i < 32; i += 8) {
    int k = k0 + ty + i, t = t0 + tx;
    if (k < KK && t < DD) xt[((size_t)b * KK + k) * DD + t] = tile[tx][ty + i];
  }
}

// first zero index (else D) per sequence + length histogram
__global__ __launch_bounds__(64) void compute_lengths(const float* __restrict__ xt,
                                                      int* __restrict__ lengths,
                                                      int* __restrict__ hist) {
  int n = blockIdx.x, lane = threadIdx.x;
  int m = DD;
  for (int t = lane; t < DD; t += 64) {
    if (xt[(size_t)n * DD + t] == 0.0f) { m = t; break; }
  }
#pragma unroll
  for (int off = 1; off < 64; off <<= 1) {
    int o = __shfl_xor(m, off, 64);
    m = (o < m) ? o : m;
  }
  if (lane == 0) {
    lengths[n] = m;
    atomicAdd(&hist[m], 1);
  }
}

// wave-parallel exclusive prefix scan over 512 bins (8 bins/lane + shfl scan)
__global__ __launch_bounds__(64) void scan_offsets(const int* __restrict__ hist,
                                                   int* __restrict__ offs) {
  int lane = threadIdx.x;
  int v[8], tot = 0;
#pragma unroll
  for (int i = 0; i < 8; ++i) { v[i] = tot; tot += hist[lane * 8 + i]; }
  int incl = tot;
#pragma unroll
  for (int off = 1; off < 64; off <<= 1) {
    int oth = __shfl_up(incl, off, 64);
    if (lane >= off) incl += oth;
  }
  int excl = incl - tot;
#pragma unroll
  for (int i = 0; i < 8; ++i) offs[lane * 8 + i] = excl + v[i];
}

__global__ __launch_bounds__(256) void scatter_sort(const int* __restrict__ lengths,
                                                    int* __restrict__ offs,
                                                    int* __restrict__ order,
                                                    int* __restrict__ len_sorted) {
  int n = blockIdx.x * 256 + threadIdx.x;
  if (n >= NN) return;
  int len = lengths[n];
  int pos = atomicAdd(&offs[len], 1);
  order[pos] = n;
  len_sorted[pos] = len;
}

// SIMD-aware wave->octet mapping (1 wave per block; XCD round-robin means
// p and p+NSIMD co-reside). Singles get longest octets; pairs sum ~constant.
__device__ __forceinline__ int octet_of_wave(int p, int W) {
  int E = W - NSIMD;
  if (E <= 0) return W - 1 - p;                 // all singles: desc
  if (p >= NSIMD) return p - NSIMD;             // pair minor: shortest E
  if (p >= E) return W - 1 - (p - E);           // singles: longest
  return (W - 1 - NSIMD + E) - p;               // pair major
}

// ===== dir-major slab layout =====
// buf[oct4][t][dir][32] halfs; slot (sg&3)*8+li. Wave-step store -> 2
// contiguous 64B segments. Consumer reads 16B at +0 (fwd) / +64B (bwd).

// 8 lanes per (sorted-seq, dir); lane li owns hidden unit li. 1 wave per block.
// amdgpu_waves_per_eu(2,2): we use exactly 2 waves/SIMD -> tell the backend
// occupancy beyond 2 is worthless, so it keeps weights + the 4-deep prefetch
// register-resident instead of sinking loads to minimize VGPR pressure.
template <int IN_DIM, bool IND_IN, bool WRITE_SEQ, bool FWD_ONLY>
__global__ __attribute__((amdgpu_waves_per_eu(2, 2))) __launch_bounds__(64)
void gru_scan(
    const void* __restrict__ in, half_t* __restrict__ out, float* __restrict__ feat,
    const int* __restrict__ len_sorted, const int* __restrict__ order,
    const float* __restrict__ Wih, const float* __restrict__ Whh,
    const float* __restrict__ bih, const float* __restrict__ bhh, int nseq) {
  int p = blockIdx.x;                 // one wave per block
  int lane = threadIdx.x & 63;
  int G = FWD_ONLY ? nseq : nseq * 2;
  int W = (G + 7) >> 3;
  if (p >= W) return;
  int o = octet_of_wave(p, W);
  int gidx = o * 8 + (lane >> 3);
  int li = lane & 7;
  if (gidx >= G) return;
  int sg  = FWD_ONLY ? gidx : (gidx >> 1);
  int dir = FWD_ONLY ? 0 : (gidx & 1);
  int len = len_sorted[sg];

  int qb = li & 4;
  int wp[3][4];       // packed f16x2 {Whh[.,qb+P], Whh[.,(qb+P)^7]}
  f16x2 wi2[3][8];
  float wi1[3];
  float bs[3], bh2;   // bs[0..1] = bih+bhh, bs[2] = bih; bh2 = bhh n-gate
#pragma unroll
  for (int gt = 0; gt < 3; ++gt) {
    int row = dir * 24 + gt * 8 + li;
    if constexpr (IN_DIM == 16) {
#pragma unroll
      for (int q = 0; q < 8; ++q) {
        f16x2 w;
        w.x = (half_t)Wih[row * 16 + 2 * q];
        w.y = (half_t)Wih[row * 16 + 2 * q + 1];
        wi2[gt][q] = w;
      }
    } else {
      wi1[gt] = Wih[row];
    }
#pragma unroll
    for (int P = 0; P < 4; ++P)
      wp[gt][P] = pkh(Whh[row * 8 + qb + P], Whh[row * 8 + ((qb + P) ^ 7)]);
    bs[gt] = bih[row] + ((gt < 2) ? bhh[row] : 0.0f);
    if (gt == 2) bh2 = bhh[row];
  }

  int steps = len;  // >= 200 always
  float h = 0.0f;

  const float* px = nullptr;
  const half_t* pxh = nullptr;
  ptrdiff_t xstep;
  if constexpr (IN_DIM == 1) {
    const float* basep = (const float*)in + (IND_IN ? (size_t)order[sg] * DD : (size_t)sg * DD);
    px = basep + ((dir == 0) ? 0 : (len - 1));
    xstep = (dir == 0) ? 1 : -1;
  } else {
    const half_t* basep = (const half_t*)in + (size_t)(sg >> 2) * DD * 64 + (sg & 3) * 8;
    pxh = basep + (size_t)((dir == 0) ? 0 : (len - 1)) * 64;
    xstep = (dir == 0) ? 64 : -64;
  }

  half_t* pw = nullptr; ptrdiff_t wstep = 0;
  if constexpr (WRITE_SEQ) {
    pw = out + ((size_t)(sg >> 2) * DD + ((dir == 0) ? 0 : (len - 1))) * 64
             + dir * 32 + (sg & 3) * 8 + li;
    wstep = (dir == 0) ? 64 : -64;
  }

  // epilogue: packed-f16 h-gather + dot2 gh (r/z chains SEEDED with gi), store
  auto core = [&](float a0, float a1, float a2) {
    float hm = HMIRROR(h);
    int hp = pkh(h, hm);               // {h(own), h(lane^7)}
    f16x2 u0 = bc16(QPERMI(hp, 0));
    f16x2 u1 = bc16(QPERMI(hp, 1));
    f16x2 u2 = bc16(QPERMI(hp, 2));
    f16x2 u3 = bc16(QPERMI(hp, 3));

    float c0 = dot2(bc16(wp[0][3]), u3, dot2(bc16(wp[0][2]), u2,
               dot2(bc16(wp[0][1]), u1, dot2(bc16(wp[0][0]), u0, a0))));
    float c1 = dot2(bc16(wp[1][3]), u3, dot2(bc16(wp[1][2]), u2,
               dot2(bc16(wp[1][1]), u1, dot2(bc16(wp[1][0]), u0, a1))));
    float c2 = dot2(bc16(wp[2][3]), u3, dot2(bc16(wp[2][2]), u2,
               dot2(bc16(wp[2][1]), u1, dot2(bc16(wp[2][0]), u0, bh2))));

    float r = fast_sigmoid(c0);
    float z = fast_sigmoid(c1);
    float n = fast_tanh(a2 + r * c2);
    h = z * (h - n) + n;  // == (1-z)*n + z*h
    if constexpr (WRITE_SEQ) { *pw = (half_t)h; pw += wstep; }
  };

  if constexpr (IN_DIM == 1) {
    float s0_, s1_, s2_, s3_;
    auto ld = [&](float& S_) { S_ = *px; px += xstep; };
    auto st = [&](float& S_, bool pf) {
      float a0 = fmaf(wi1[0], S_, bs[0]);
      float a1 = fmaf(wi1[1], S_, bs[1]);
      float a2 = fmaf(wi1[2], S_, bs[2]);
      if (pf) ld(S_);
      core(a0, a1, a2);
    };
    ld(s0_); ld(s1_); ld(s2_); ld(s3_);
    int t = 0;
    for (; t + 4 <= steps; t += 4) {
      st(s0_, true); st(s1_, true); st(s2_, true); st(s3_, true);
    }
    int rem = steps - t;
    if (rem > 0) st(s0_, false);
    if (rem > 1) st(s1_, false);
    if (rem > 2) st(s2_, false);
  } else {
    uint4 b0_[2], b1_[2], b2_[2], b3_[2];
    auto ld = [&](uint4 (&B_)[2]) {
      const uint4* q4 = reinterpret_cast<const uint4*>(pxh);
      B_[0] = q4[0]; B_[1] = q4[4];   // fwd dims, bwd dims (+64B)
      pxh += xstep;
    };
    auto st = [&](uint4 (&B_)[2], bool pf) {
      float a0 = bs[0], a1 = bs[1], a2 = bs[2];
#pragma unroll
      for (int q = 0; q < 2; ++q) {
        f16x2 p0 = __builtin_bit_cast(f16x2, B_[q].x);
        f16x2 p1 = __builtin_bit_cast(f16x2, B_[q].y);
        f16x2 p2 = __builtin_bit_cast(f16x2, B_[q].z);
        f16x2 p3 = __builtin_bit_cast(f16x2, B_[q].w);
        a0 = dot2(wi2[0][4*q], p0, a0); a0 = dot2(wi2[0][4*q+1], p1, a0);
        a0 = dot2(wi2[0][4*q+2], p2, a0); a0 = dot2(wi2[0][4*q+3], p3, a0);
        a1 = dot2(wi2[1][4*q], p0, a1); a1 = dot2(wi2[1][4*q+1], p1, a1);
        a1 = dot2(wi2[1][4*q+2], p2, a1); a1 = dot2(wi2[1][4*q+3], p3, a1);
        a2 = dot2(wi2[2][4*q], p0, a2); a2 = dot2(wi2[2][4*q+1], p1, a2);
        a2 = dot2(wi2[2][4*q+2], p2, a2); a2 = dot2(wi2[2][4*q+3], p3, a2);
      }
      if (pf) ld(B_);
      core(a0, a1, a2);
    };
    ld(b0_); ld(b1_); ld(b2_); ld(b3_);
    int t = 0;
    for (; t + 4 <= steps; t += 4) {
      st(b0_, true); st(b1_, true); st(b2_, true); st(b3_, true);
    }
    int rem = steps - t;
    if (rem > 0) st(b0_, false);
    if (rem > 1) st(b1_, false);
    if (rem > 2) st(b2_, false);
  }

  if constexpr (!WRITE_SEQ) {
    feat[(size_t)order[sg] * 16 + dir * 8 + li] = h;
  }
}

// last layer, bwd direction: only t = len-1 matters and h0 = 0 => gh = bhh
__global__ __launch_bounds__(256) void bwd_last(
    const half_t* __restrict__ in, float* __restrict__ feat,
    const int* __restrict__ len_sorted, const int* __restrict__ order,
    const float* __restrict__ Wih, const float* __restrict__ bih,
    const float* __restrict__ bhh, int nseq) {
  int tid = blockIdx.x * blockDim.x + threadIdx.x;
  int sg = tid >> 3, li = tid & 7;
  if (sg >= nseq) return;
  int len = len_sorted[sg];
  const half_t* xp = in + ((size_t)(sg >> 2) * DD + (len - 1)) * 64 + (sg & 3) * 8;
  float xv[16];
#pragma unroll
  for (int j = 0; j < 8; ++j) { xv[j] = (float)xp[j]; xv[8 + j] = (float)xp[32 + j]; }
  float a[3], bh[3];
#pragma unroll
  for (int gt = 0; gt < 3; ++gt) {
    int row = 24 + gt * 8 + li;  // dir=1 rows
    const float* wpp = Wih + row * 16;
    float acc = bih[row];
#pragma unroll
    for (int j = 0; j < 16; ++j) acc = fmaf(wpp[j], xv[j], acc);
    a[gt] = acc;
    bh[gt] = bhh[row];
  }
  float r = fast_sigmoid(a[0] + bh[0]);
  float z = fast_sigmoid(a[1] + bh[1]);
  float n = fast_tanh(a[2] + r * bh[2]);
  float h = (1.0f - z) * n;
  feat[(size_t)order[sg] * 16 + 8 + li] = h;
}

__global__ __launch_bounds__(256) void head_kernel(
    const float* __restrict__ feat, const float* __restrict__ w1,
    const float* __restrict__ b1, const float* __restrict__ w2,
    const float* __restrict__ b2, float* __restrict__ out) {
  int n = blockIdx.x * blockDim.x + threadIdx.x;
  if (n >= NN) return;
  float f[16];
  const float4* p = reinterpret_cast<const float4*>(feat + (size_t)n * 16);
#pragma unroll
  for (int q = 0; q < 4; ++q) {
    float4 v = p[q];
    f[4*q] = v.x; f[4*q+1] = v.y; f[4*q+2] = v.z; f[4*q+3] = v.w;
  }
  float y[8];
#pragma unroll
  for (int o = 0; o < 8; ++o) {
    float s = b1[o];
#pragma unroll
    for (int j = 0; j < 16; ++j) s += f[j] * w1[o * 16 + j];
    y[o] = (s > 0.0f) ? s : 0.2f * s;
  }
#pragma unroll
  for (int o2 = 0; o2 < 8; ++o2) {
    float s = b2[o2];
#pragma unroll
    for (int o = 0; o < 8; ++o) s += y[o] * w2[o2 * 8 + o];
    out[(size_t)n * 8 + o2] = s;
  }
}

extern "C" void kernel_launch(void* const* d_in, const int* in_sizes, int n_in,
                              void* d_out, int out_size, void* d_ws, size_t ws_size,
                              hipStream_t stream) {
  const float* x      = (const float*)d_in[0];
  const float* w_ih0  = (const float*)d_in[1];
  const float* w_hh0  = (const float*)d_in[2];
  const float* b_ih0  = (const float*)d_in[3];
  const float* b_hh0  = (const float*)d_in[4];
  const float* w_ih   = (const float*)d_in[5];
  const float* w_hh   = (const float*)d_in[6];
  const float* b_ih   = (const float*)d_in[7];
  const float* b_hh   = (const float*)d_in[8];
  const float* lin1_w = (const float*)d_in[9];
  const float* lin1_b = (const float*)d_in[10];
  const float* lin2_w = (const float*)d_in[11];
  const float* lin2_b = (const float*)d_in[12];
  float* out = (float*)d_out;

  char* ws = (char*)d_ws;
  size_t off = 0;
  auto alloc = [&](size_t bytes) -> void* {
    void* p = ws + off;
    off += (bytes + 255) & ~(size_t)255;
    return p;
  };
  alloc(1024);  // front guard (backward prefetch overrun)
  float* xt         = (float*)alloc((size_t)NN * DD * sizeof(float) + 1024);
  int*   lengths    = (int*)  alloc((size_t)NN * sizeof(int));
  int*   hist       = (int*)  alloc(NBINS * sizeof(int));
  int*   offs       = (int*)  alloc(NBINS * sizeof(int));
  int*   order      = (int*)  alloc((size_t)NN * sizeof(int));
  int*   len_sorted = (int*)  alloc((size_t)NN * sizeof(int));
  float* feat       = (float*)alloc((size_t)NN * 16 * sizeof(float));
  size_t base = off;
  size_t per_seq = (size_t)DD * 16 * sizeof(half_t) * 2 + 1024;  // two f16 buffers
  int Nc = NN;
  if (base + (size_t)NN * per_seq + 8192 > ws_size) {
    size_t avail = (ws_size > base + 8192) ? (ws_size - base - 8192) : 0;
    size_t nc = avail / per_seq;
    if (nc < 4) nc = 4;
    if (nc > (size_t)NN) nc = NN;
    Nc = (int)(nc & ~(size_t)3);  // multiple of 4 (slab oct4 granularity)
  }
  alloc(1024);  // guard before bufA
  half_t* bufA = (half_t*)alloc((size_t)Nc * DD * 16 * sizeof(half_t) + 1024);
  half_t* bufB = (half_t*)alloc((size_t)Nc * DD * 16 * sizeof(half_t) + 1024);

  hipMemsetAsync(hist, 0, NBINS * sizeof(int), stream);
  dim3 gT(BB, (DD + 31) / 32, (KK + 31) / 32), bT(32, 8, 1);
  hipLaunchKernelGGL(transpose_x, gT, bT, 0, stream, x, xt);
  hipLaunchKernelGGL(compute_lengths, dim3(NN), dim3(64), 0, stream, xt, lengths, hist);
  hipLaunchKernelGGL(scan_offsets, dim3(1), dim3(64), 0, stream, hist, offs);
  hipLaunchKernelGGL(scatter_sort, dim3((NN + 255) / 256), dim3(256), 0, stream,
                     lengths, offs, order, len_sorted);

  for (int s0 = 0; s0 < NN; s0 += Nc) {
    int ns = (NN - s0 < Nc) ? (NN - s0) : Nc;
    int W2 = (ns * 2 + 7) / 8;           // bidir wave count (1 wave per block)
    int W1 = (ns + 7) / 8;               // fwd-only wave count
    int blk1 = (ns * 8 + 255) / 256;     // bwd_last
    gru_scan<1, true, true, false><<<W2, 64, 0, stream>>>(
        (const void*)xt, bufA, nullptr, len_sorted + s0, order + s0,
        w_ih0, w_hh0, b_ih0, b_hh0, ns);
    gru_scan<16, false, true, false><<<W2, 64, 0, stream>>>(
        (const void*)bufA, bufB, nullptr, len_sorted + s0, order + s0,
        w_ih + 0 * 2 * 24 * 16, w_hh + 0 * 2 * 24 * 8,
        b_ih + 0 * 2 * 24, b_hh + 0 * 2 * 24, ns);
    gru_scan<16, false, true, false><<<W2, 64, 0, stream>>>(
        (const void*)bufB, bufA, nullptr, len_sorted + s0, order + s0,
        w_ih + 1 * 2 * 24 * 16, w_hh + 1 * 2 * 24 * 8,
        b_ih + 1 * 2 * 24, b_hh + 1 * 2 * 24, ns);
    gru_scan<16, false, false, true><<<W1, 64, 0, stream>>>(
        (const void*)bufA, nullptr, feat, len_sorted + s0, order + s0,
        w_ih + 2 * 2 * 24 * 16, w_hh + 2 * 2 * 24 * 8,
        b_ih + 2 * 2 * 24, b_hh + 2 * 2 * 24, ns);
    hipLaunchKernelGGL(bwd_last, dim3(blk1), dim3(256), 0, stream,
                       bufA, feat, len_sorted + s0, order + s0,
                       w_ih + 2 * 2 * 24 * 16, b_ih + 2 * 2 * 24, b_hh + 2 * 2 * 24, ns);
  }
  hipLaunchKernelGGL(head_kernel, dim3((NN + 255) / 256), dim3(256), 0, stream,
                     feat, lin1_w, lin1_b, lin2_w, lin2_b, out);
}